// Round 1
// baseline (297.595 us; speedup 1.0000x reference)
//
#include <hip/hip_runtime.h>
#include <hip/hip_bf16.h>
#include <math.h>

#define T_TOKENS 16384
#define HDIM     2048
#define NEXP     128
#define TOPK     8

#define TB 32            // tokens per workgroup
#define BK 64            // k-chunk
#define XS_STRIDE 68     // padded (16B-aligned) x-tile row stride in floats

// ---------------- kernel 0: one-time W transpose W[e][h] -> WT[h][e] ----------------
__global__ __launch_bounds__(256) void transpose_w(const float* __restrict__ w,
                                                   float* __restrict__ wt) {
    int idx = blockIdx.x * 256 + threadIdx.x;       // 0 .. 2048*128-1
    int e = idx & (NEXP - 1);
    int h = idx >> 7;
    wt[idx] = w[e * HDIM + h];                      // writes coalesced; reads L2-served (1 MB)
}

// ---------------- kernel 1: logits = x @ W^T (fp32, VALU) ----------------
__global__ __launch_bounds__(256) void gemm_logits(const float* __restrict__ x,
                                                   const float* __restrict__ wt,
                                                   float* __restrict__ logits) {
    __shared__ float xs[TB][XS_STRIDE];   // x tile, token-major (reads are uniform-k broadcast)
    __shared__ float ws[BK][NEXP];        // W tile, k-major (reads uniform-k, contiguous dwords)

    const int tid = threadIdx.x;
    const long token0 = (long)blockIdx.x * TB;
    const float* xg = x + token0 * HDIM;

    const int tg = tid >> 5;   // token group (4 tokens), 0..7
    const int eg = tid & 31;   // expert group (4 experts), 0..31

    float acc[4][4];
#pragma unroll
    for (int i = 0; i < 4; ++i)
#pragma unroll
        for (int j = 0; j < 4; ++j) acc[i][j] = 0.f;

    for (int k0 = 0; k0 < HDIM; k0 += BK) {
        // stage x: 32x64 floats = 512 float4 / 256 threads = 2 each (coalesced)
#pragma unroll
        for (int it = 0; it < 2; ++it) {
            int f = tid + it * 256;
            int t = f >> 4, c = f & 15;
            float4 v = *(const float4*)(xg + (long)t * HDIM + k0 + 4 * c);
            *(float4*)(&xs[t][4 * c]) = v;
        }
        // stage W chunk: WT rows k0..k0+63 are 32 KB contiguous (coalesced, L2-hot)
#pragma unroll
        for (int it = 0; it < 8; ++it) {
            int f = tid + it * 256;
            int k = f >> 5, e4 = f & 31;
            float4 v = *(const float4*)(wt + (long)(k0 + k) * NEXP + 4 * e4);
            *(float4*)(&ws[k][4 * e4]) = v;
        }
        __syncthreads();

        // chunk accumulator (pairwise-ish grouping for better fp32 accuracy)
        float cacc[4][4];
#pragma unroll
        for (int i = 0; i < 4; ++i)
#pragma unroll
            for (int j = 0; j < 4; ++j) cacc[i][j] = 0.f;

#pragma unroll
        for (int k = 0; k < BK; k += 4) {
            float4 xa[4], wa[4];
#pragma unroll
            for (int i = 0; i < 4; ++i) xa[i] = *(const float4*)(&xs[4 * tg + i][k]);
#pragma unroll
            for (int kk = 0; kk < 4; ++kk) wa[kk] = *(const float4*)(&ws[k + kk][4 * eg]);
#pragma unroll
            for (int i = 0; i < 4; ++i) {
                const float xv0 = xa[i].x, xv1 = xa[i].y, xv2 = xa[i].z, xv3 = xa[i].w;
                cacc[i][0] += xv0 * wa[0].x; cacc[i][1] += xv0 * wa[0].y;
                cacc[i][2] += xv0 * wa[0].z; cacc[i][3] += xv0 * wa[0].w;
                cacc[i][0] += xv1 * wa[1].x; cacc[i][1] += xv1 * wa[1].y;
                cacc[i][2] += xv1 * wa[1].z; cacc[i][3] += xv1 * wa[1].w;
                cacc[i][0] += xv2 * wa[2].x; cacc[i][1] += xv2 * wa[2].y;
                cacc[i][2] += xv2 * wa[2].z; cacc[i][3] += xv2 * wa[2].w;
                cacc[i][0] += xv3 * wa[3].x; cacc[i][1] += xv3 * wa[3].y;
                cacc[i][2] += xv3 * wa[3].z; cacc[i][3] += xv3 * wa[3].w;
            }
        }
#pragma unroll
        for (int i = 0; i < 4; ++i)
#pragma unroll
            for (int j = 0; j < 4; ++j) acc[i][j] += cacc[i][j];
        __syncthreads();
    }

    // write logits [T][128]
#pragma unroll
    for (int i = 0; i < 4; ++i) {
        float4 r = make_float4(acc[i][0], acc[i][1], acc[i][2], acc[i][3]);
        *(float4*)(logits + (token0 + 4 * tg + i) * NEXP + 4 * eg) = r;
    }
}

// ---------------- kernel 2: top-8 + renormalized softmax (== softmax over top-8) ----------------
__global__ __launch_bounds__(256) void topk_softmax(const float* __restrict__ logits,
                                                    float* __restrict__ out_idx,
                                                    float* __restrict__ out_w) {
    const int lane = threadIdx.x & 63;
    const int wid = threadIdx.x >> 6;
    const long t = (long)blockIdx.x * 4 + wid;
    const float* lg = logits + t * NEXP;

    float2 v = *(const float2*)(lg + 2 * lane);
    float v0 = v.x, v1 = v.y;
    const int i0 = 2 * lane, i1 = 2 * lane + 1;

    float topv[TOPK];
    int topi[TOPK];
#pragma unroll
    for (int s = 0; s < TOPK; ++s) {
        // local argmax of this lane's two slots (tie -> smaller index)
        float mv = (v0 >= v1) ? v0 : v1;
        int mi = (v0 >= v1) ? i0 : i1;
        // wave-wide butterfly argmax, tie -> smaller index (matches lax.top_k)
#pragma unroll
        for (int off = 32; off >= 1; off >>= 1) {
            float ov = __shfl_xor(mv, off);
            int oi = __shfl_xor(mi, off);
            if (ov > mv || (ov == mv && oi < mi)) { mv = ov; mi = oi; }
        }
        topv[s] = mv; topi[s] = mi;
        if (i0 == mi) v0 = -INFINITY;
        if (i1 == mi) v1 = -INFINITY;
    }

    // softmax over the 8 selected logits (all lanes hold identical topv/topi)
    const float m = topv[0];
    float sum = 0.f;
#pragma unroll
    for (int s = 0; s < TOPK; ++s) sum += expf(topv[s] - m);
    const float inv = 1.f / sum;

    float myv = topv[0]; int myi = topi[0];
#pragma unroll
    for (int s = 1; s < TOPK; ++s)
        if (lane == s) { myv = topv[s]; myi = topi[s]; }

    if (lane < TOPK) {
        out_idx[t * TOPK + lane] = (float)myi;   // idx chunk read back as float32
        out_w[t * TOPK + lane] = expf(myv - m) * inv;
    }
}

extern "C" void kernel_launch(void* const* d_in, const int* in_sizes, int n_in,
                              void* d_out, int out_size, void* d_ws, size_t ws_size,
                              hipStream_t stream) {
    const float* x = (const float*)d_in[0];   // [4,4096,2048] fp32
    const float* w = (const float*)d_in[1];   // [128,2048] fp32
    float* out = (float*)d_out;               // [T*8 idx][T*8 weights], flat fp32

    float* logits = (float*)d_ws;                       // 16384*128 fp32 = 8 MB
    float* wt = logits + (size_t)T_TOKENS * NEXP;       // 2048*128 fp32 = 1 MB

    transpose_w<<<(HDIM * NEXP) / 256, 256, 0, stream>>>(w, wt);
    gemm_logits<<<T_TOKENS / TB, 256, 0, stream>>>(x, wt, logits);
    topk_softmax<<<T_TOKENS / 4, 256, 0, stream>>>(logits, out, out + (size_t)T_TOKENS * TOPK);
}